// Round 2
// baseline (920.760 us; speedup 1.0000x reference)
//
#include <hip/hip_runtime.h>

// 2:4 structured sparsity over channel groups of x:[64,512,56,56] fp32.
// Memory-bound streaming: 411 MB read + 411 MB write, zero reuse.
// R1: 4x thread coarsening (16 spatial floats x 4 channels per thread ->
// 4 KB contiguous burst per plane per wave) + nontemporal hints (no L2
// allocation for a pure stream).

typedef float f4 __attribute__((ext_vector_type(4)));

namespace {
constexpr int kHW      = 56 * 56;          // 3136 floats per channel-plane (contiguous)
constexpr int kChunks  = kHW / 16;         // 196 chunks of 16 floats per plane
constexpr int kC       = 512;
constexpr int kG       = kC / 4;           // 128 groups of 4 channels
constexpr int kN       = 64;
constexpr int kThreads = kN * kG * kChunks;  // 1,605,632 threads
constexpr int kBlock   = 256;                // -> 6272 blocks exactly
}  // namespace

// Keep rule replicating jax top_k tie-break (drop 2 smallest |x|, lower index
// dropped first on ties): keep i iff #{j: a_j > a_i || (a_j==a_i && j>i)} < 2.
__device__ __forceinline__ void mask_quad(float& x0, float& x1, float& x2, float& x3) {
    float a0 = fabsf(x0), a1 = fabsf(x1), a2 = fabsf(x2), a3 = fabsf(x3);
    int c0 = (a1 >= a0) + (a2 >= a0) + (a3 >= a0);
    int c1 = (a0 >  a1) + (a2 >= a1) + (a3 >= a1);
    int c2 = (a0 >  a2) + (a1 >  a2) + (a3 >= a2);
    int c3 = (a0 >  a3) + (a1 >  a3) + (a2 >  a3);
    x0 = (c0 < 2) ? x0 : 0.0f;
    x1 = (c1 < 2) ? x1 : 0.0f;
    x2 = (c2 < 2) ? x2 : 0.0f;
    x3 = (c3 < 2) ? x3 : 0.0f;
}

__global__ __launch_bounds__(kBlock) void sp24_kernel(const float* __restrict__ x,
                                                      float* __restrict__ out) {
    int t = blockIdx.x * kBlock + threadIdx.x;
    // t -> (n, g, chunk): chunk fastest so consecutive lanes stream consecutive 64 B.
    int c    = t % kChunks;
    int rest = t / kChunks;
    int g    = rest & (kG - 1);
    int n    = rest >> 7;

    size_t base = (size_t)(n * kC + g * 4) * kHW + (size_t)c * 16;

    f4 v[4][4];  // [plane][16-float chunk as 4x f4]
#pragma unroll
    for (int p = 0; p < 4; ++p) {
        const f4* src = reinterpret_cast<const f4*>(x + base + (size_t)p * kHW);
#pragma unroll
        for (int q = 0; q < 4; ++q) v[p][q] = __builtin_nontemporal_load(src + q);
    }

#pragma unroll
    for (int q = 0; q < 4; ++q) {
#pragma unroll
        for (int e = 0; e < 4; ++e) {
            float e0 = v[0][q][e], e1 = v[1][q][e], e2 = v[2][q][e], e3 = v[3][q][e];
            mask_quad(e0, e1, e2, e3);
            v[0][q][e] = e0; v[1][q][e] = e1; v[2][q][e] = e2; v[3][q][e] = e3;
        }
    }

#pragma unroll
    for (int p = 0; p < 4; ++p) {
        f4* dst = reinterpret_cast<f4*>(out + base + (size_t)p * kHW);
#pragma unroll
        for (int q = 0; q < 4; ++q) __builtin_nontemporal_store(v[p][q], dst + q);
    }
}

extern "C" void kernel_launch(void* const* d_in, const int* in_sizes, int n_in,
                              void* d_out, int out_size, void* d_ws, size_t ws_size,
                              hipStream_t stream) {
    const float* x = (const float*)d_in[0];
    float* out = (float*)d_out;
    sp24_kernel<<<kThreads / kBlock, kBlock, 0, stream>>>(x, out);
}